// Round 1
// baseline (430.206 us; speedup 1.0000x reference)
//
#include <hip/hip_runtime.h>

typedef _Float16 v8h __attribute__((ext_vector_type(8)));
typedef float    v4f __attribute__((ext_vector_type(4)));

#define MFMA16(A,B,C) __builtin_amdgcn_mfma_f32_16x16x32_f16((A),(B),(C),0,0,0)

__device__ __forceinline__ float sigf(float x) {
    // sigmoid(x) = 1/(1+exp(-x)); saturates correctly at +/-inf
    return __builtin_amdgcn_rcpf(1.0f + __expf(-x));
}
__device__ __forceinline__ float tanh_f(float x) {
    return fmaf(2.0f, sigf(2.0f * x), -1.0f);
}

#define RPB 16   // rows per block
#define TT  256  // timesteps
#define HH  64   // hidden

__global__ __launch_bounds__(256, 1)
void lstm2_kernel(const float* __restrict__ x,     // [4096][256]
                  const float* __restrict__ Wih0,  // [256][1]
                  const float* __restrict__ Whh0,  // [256][64]
                  const float* __restrict__ bih0,
                  const float* __restrict__ bhh0,
                  const float* __restrict__ Wih1,  // [256][64]
                  const float* __restrict__ Whh1,  // [256][64]
                  const float* __restrict__ bih1,
                  const float* __restrict__ bhh1,
                  const float* __restrict__ Wlin,  // [64][64]
                  const float* __restrict__ blin,  // [64]
                  float* __restrict__ out)         // [4096][64]
{
    // LDS: ~30 KB total
    __shared__ float xl[TT][RPB];                       // x transposed [t][m]
    __shared__ __align__(16) _Float16 haHi[RPB][72];    // stride 72 f16 = 144B (16B-aligned, banks balanced)
    __shared__ __align__(16) _Float16 haLo[RPB][72];
    __shared__ __align__(16) _Float16 hbHi[RPB][72];
    __shared__ __align__(16) _Float16 hbLo[RPB][72];
    __shared__ float hbF[RPB][HH];                      // final-step hb in fp32

    const int tid  = threadIdx.x;
    const int w    = tid >> 6;      // wave 0..3 -> j-range
    const int l    = tid & 63;
    const int l15  = l & 15;
    const int q    = l >> 4;        // quad within wave
    const int row0 = (int)blockIdx.x * RPB;

    // ---- preload x transposed (coalesced global, strided LDS) ----
    for (int idx = tid; idx < RPB * TT; idx += 256) {
        int m = idx >> 8;
        int t = idx & (TT - 1);
        xl[t][m] = x[(row0 + m) * TT + t];
    }
    // ---- zero h state (h0 = 0) ----
    for (int idx = tid; idx < RPB * 72; idx += 256) {
        int m = idx / 72, k = idx % 72;
        haHi[m][k] = (_Float16)0.f; haLo[m][k] = (_Float16)0.f;
        hbHi[m][k] = (_Float16)0.f; hbLo[m][k] = (_Float16)0.f;
    }

    // ---- per-lane constants + register-stationary weight B-fragments ----
    // gate column for tile tau: n = tau*64 + w*16 + l15  (tau = gate type i,f,g,o)
    float wi0[4], b0c[4], b1c[4];
    v8h wh0[4][2], wi1[4][2], wh1[4][2];   // 96 VGPRs of weights / lane
    #pragma unroll
    for (int tau = 0; tau < 4; tau++) {
        int n = tau * 64 + w * 16 + l15;
        wi0[tau] = Wih0[n];
        b0c[tau] = bih0[n] + bhh0[n];
        b1c[tau] = bih1[n] + bhh1[n];
        #pragma unroll
        for (int kk = 0; kk < 2; kk++) {
            int k0 = kk * 32 + q * 8;     // B-frag: lane holds B[k=k0..k0+7][n], n=lane&15
            v8h a, b, c;
            #pragma unroll
            for (int j = 0; j < 8; j++) {
                a[j] = (_Float16)Whh0[n * HH + k0 + j];
                b[j] = (_Float16)Wih1[n * HH + k0 + j];
                c[j] = (_Float16)Whh1[n * HH + k0 + j];
            }
            wh0[tau][kk] = a; wi1[tau][kk] = b; wh1[tau][kk] = c;
        }
    }

    float ca[4] = {0.f, 0.f, 0.f, 0.f};   // c-state lives in-lane: (m = q*4+r, j = w*16+l15)
    float cb[4] = {0.f, 0.f, 0.f, 0.f};
    const int jj = w * 16 + l15;

    __syncthreads();

    for (int t = 0; t < TT; t++) {
        v4f xv = *(const v4f*)&xl[t][q * 4];   // x[m=q*4+r][t]

        // ================= layer 0: G = pre + ha @ Whh0^T =================
        v4f acc[4];
        #pragma unroll
        for (int tau = 0; tau < 4; tau++) {
            #pragma unroll
            for (int r = 0; r < 4; r++) acc[tau][r] = fmaf(xv[r], wi0[tau], b0c[tau]);
        }
        // A-frags: lane reads A[m=l15][k=q*8+j (+32)]
        v8h aHi0 = *(const v8h*)&haHi[l15][q * 8];
        v8h aHi1 = *(const v8h*)&haHi[l15][32 + q * 8];
        v8h aLo0 = *(const v8h*)&haLo[l15][q * 8];
        v8h aLo1 = *(const v8h*)&haLo[l15][32 + q * 8];
        #pragma unroll
        for (int tau = 0; tau < 4; tau++) {
            acc[tau] = MFMA16(aHi0, wh0[tau][0], acc[tau]);
            acc[tau] = MFMA16(aHi1, wh0[tau][1], acc[tau]);
            acc[tau] = MFMA16(aLo0, wh0[tau][0], acc[tau]);
            acc[tau] = MFMA16(aLo1, wh0[tau][1], acc[tau]);
        }
        // pointwise: all 4 gates for (m,j) are in this lane (tau = reg index)
        float haNew[4];
        #pragma unroll
        for (int r = 0; r < 4; r++) {
            float iv = sigf(acc[0][r]);
            float fv = sigf(acc[1][r]);
            float gv = tanh_f(acc[2][r]);
            float ov = sigf(acc[3][r]);
            ca[r] = fmaf(fv, ca[r], iv * gv);
            haNew[r] = ov * tanh_f(ca[r]);
        }
        __syncthreads();   // all waves' GEMM0 reads of ha done
        #pragma unroll
        for (int r = 0; r < 4; r++) {
            int m = q * 4 + r;
            _Float16 hi = (_Float16)haNew[r];
            haHi[m][jj] = hi;
            haLo[m][jj] = (_Float16)(haNew[r] - (float)hi);
        }
        __syncthreads();   // ha_new visible

        // ====== layer 1: G = b1 + ha_new @ Wih1^T + hb @ Whh1^T ======
        #pragma unroll
        for (int tau = 0; tau < 4; tau++) {
            #pragma unroll
            for (int r = 0; r < 4; r++) acc[tau][r] = b1c[tau];
        }
        aHi0 = *(const v8h*)&haHi[l15][q * 8];
        aHi1 = *(const v8h*)&haHi[l15][32 + q * 8];
        aLo0 = *(const v8h*)&haLo[l15][q * 8];
        aLo1 = *(const v8h*)&haLo[l15][32 + q * 8];
        v8h bHi0 = *(const v8h*)&hbHi[l15][q * 8];
        v8h bHi1 = *(const v8h*)&hbHi[l15][32 + q * 8];
        v8h bLo0 = *(const v8h*)&hbLo[l15][q * 8];
        v8h bLo1 = *(const v8h*)&hbLo[l15][32 + q * 8];
        #pragma unroll
        for (int tau = 0; tau < 4; tau++) {
            acc[tau] = MFMA16(aHi0, wi1[tau][0], acc[tau]);
            acc[tau] = MFMA16(aHi1, wi1[tau][1], acc[tau]);
            acc[tau] = MFMA16(aLo0, wi1[tau][0], acc[tau]);
            acc[tau] = MFMA16(aLo1, wi1[tau][1], acc[tau]);
            acc[tau] = MFMA16(bHi0, wh1[tau][0], acc[tau]);
            acc[tau] = MFMA16(bHi1, wh1[tau][1], acc[tau]);
            acc[tau] = MFMA16(bLo0, wh1[tau][0], acc[tau]);
            acc[tau] = MFMA16(bLo1, wh1[tau][1], acc[tau]);
        }
        float hbNew[4];
        #pragma unroll
        for (int r = 0; r < 4; r++) {
            float iv = sigf(acc[0][r]);
            float fv = sigf(acc[1][r]);
            float gv = tanh_f(acc[2][r]);
            float ov = sigf(acc[3][r]);
            cb[r] = fmaf(fv, cb[r], iv * gv);
            hbNew[r] = ov * tanh_f(cb[r]);
        }
        __syncthreads();   // GEMM1 reads of hb done
        #pragma unroll
        for (int r = 0; r < 4; r++) {
            int m = q * 4 + r;
            _Float16 hi = (_Float16)hbNew[r];
            hbHi[m][jj] = hi;
            hbLo[m][jj] = (_Float16)(hbNew[r] - (float)hi);
            if (t == TT - 1) hbF[m][jj] = hbNew[r];
        }
        // no 4th barrier: next iteration's first two barriers order hb-write
        // before any GEMM1 read; GEMM0 only touches ha (stable).
    }
    __syncthreads();

    // ---- out[m][n] = hb_last[m][:] . Wlin[n][:] + blin[n]  (fp32, one-time) ----
    int m  = tid >> 4;
    int n0 = (tid & 15) * 4;
    float accO[4] = {blin[n0], blin[n0 + 1], blin[n0 + 2], blin[n0 + 3]};
    #pragma unroll 8
    for (int j = 0; j < HH; j++) {
        float h = hbF[m][j];
        #pragma unroll
        for (int d = 0; d < 4; d++)
            accO[d] = fmaf(h, Wlin[(n0 + d) * HH + j], accO[d]);
    }
    v4f ov = {accO[0], accO[1], accO[2], accO[3]};
    *(v4f*)&out[(row0 + m) * HH + n0] = ov;
}

extern "C" void kernel_launch(void* const* d_in, const int* in_sizes, int n_in,
                              void* d_out, int out_size, void* d_ws, size_t ws_size,
                              hipStream_t stream) {
    const float* x    = (const float*)d_in[0];
    const float* Wih0 = (const float*)d_in[1];
    const float* Whh0 = (const float*)d_in[2];
    const float* bih0 = (const float*)d_in[3];
    const float* bhh0 = (const float*)d_in[4];
    const float* Wih1 = (const float*)d_in[5];
    const float* Whh1 = (const float*)d_in[6];
    const float* bih1 = (const float*)d_in[7];
    const float* bhh1 = (const float*)d_in[8];
    const float* Wlin = (const float*)d_in[9];
    const float* blin = (const float*)d_in[10];
    // B=4096 rows / 16 rows per block = 256 blocks (1 per CU)
    lstm2_kernel<<<256, 256, 0, stream>>>(x, Wih0, Whh0, bih0, bhh0,
                                          Wih1, Whh1, bih1, bhh1,
                                          Wlin, blin, (float*)d_out);
}